// Round 16
// baseline (152.453 us; speedup 1.0000x reference)
//
#include <hip/hip_runtime.h>
#include <hip/hip_fp16.h>

#define N_NODES 50000
#define N_EDGES 800000
#define D_IN 128
#define HH 4
#define FF 16
#define HF 64  // HH*FF
#define NBUCKETS 392                 // ceil(N_NODES/128); bucket b covers dst in [b*128, b*128+128)
#define BCAP 2560                    // bucket capacity; Poisson(2048) + 11 sigma
#define CHUNK 2048                   // edges per bin block
#define NBIN_BLOCKS ((N_EDGES + CHUNK - 1) / CHUNK)  // 391
#define GEMM_BLOCKS ((N_NODES + 63) / 64)            // 782
#define SORT_K (BCAP / 256)                          // 10 recs per thread in sort

struct __align__(8) Half4 { __half2 a, b; };

typedef _Float16 half2_v __attribute__((ext_vector_type(2)));
struct __align__(8) H4 { half2_v a, b; };

__device__ __forceinline__ float dot2acc(half2_v a, half2_v b, float acc) {
#if __has_builtin(__builtin_amdgcn_fdot2)
    return __builtin_amdgcn_fdot2(a, b, acc, false);
#else
    return acc + (float)a[0] * (float)b[0] + (float)a[1] * (float)b[1];
#endif
}

__device__ __forceinline__ float dot4h(H4 a, H4 v) {
    return dot2acc(a.a, v.a, dot2acc(a.b, v.b, 0.0f));
}

// 256-entry exclusive scan with 2 barriers: wave shfl_up scan + 4-wave combine.
__device__ __forceinline__ int block_excl_scan(int val, int* wsum) {
    int lane = threadIdx.x & 63;
    int wave = threadIdx.x >> 6;
    int incl = val;
#pragma unroll
    for (int off = 1; off < 64; off <<= 1) {
        int t = __shfl_up(incl, off, 64);
        if (lane >= off) incl += t;
    }
    if (lane == 63) wsum[wave] = incl;
    __syncthreads();
    if (threadIdx.x == 0) {
        int a = 0;
#pragma unroll
        for (int w = 0; w < 4; ++w) { int t = wsum[w]; wsum[w] = a; a += t; }
    }
    __syncthreads();
    return incl + wsum[wave] - val;
}

// LDS union: gemm path 34.0 KB (fp16 tiles), bin path 6 KB -> 4 blocks/CU for both.
union SmemU {
    struct {
        __half As[64][132];   // stride 264 B; 4-row delta ≡ 8 words mod 32 -> conflict-free broadcast
        __half Bst[64][136];  // W transposed [col][k]; stride 272 B; 4-row delta ≡ 16 -> 2-way (free)
    } g;
    struct {
        int hist[512], cur[512], gbase[512];  // 392 used
    } b;
};

// ---------------- fused: blocks [0,391) bin edges; blocks [391,1173) GEMM ----------------
// Fusion is profitable NOW because the fp16 GEMM shrank the LDS union 66->34 KB
// (R12's fusion at 66 KB capped bin blocks at 2/CU -- R14 counters showed
// Occupancy 14.5% as the bottleneck). Bin blocks first: they feed sort.
__global__ __launch_bounds__(256, 4) void gemm_bin_kernel(const float* __restrict__ feat,
                                                          const float* __restrict__ W,
                                                          const int* __restrict__ src,
                                                          const int* __restrict__ dst,
                                                          __half* __restrict__ fth,
                                                          int* __restrict__ gcur,
                                                          int* __restrict__ recs) {
    __shared__ SmemU smem;
    int tid = threadIdx.x;

    if (blockIdx.x < NBIN_BLOCKS) {
        // ---- bin: rec = src(16b) | (dst&127)<<16 | bucket<<23 (bucket>=256 ->
        // rec NEGATIVE: never sign-test recs). hist -> global window alloc ->
        // direct global scatter at gbase[b]+cur[b]++. 3 barriers.
        int e0 = blockIdx.x * CHUNK;
        int n = N_EDGES - e0; if (n > CHUNK) n = CHUNK;

        smem.b.hist[tid] = 0;
        smem.b.hist[tid + 256] = 0;
        __syncthreads();

        int myrec[CHUNK / 256];
        int myb[CHUNK / 256];
#pragma unroll
        for (int k = 0; k < CHUNK / 256; ++k) {
            int idx = tid + k * 256;
            myb[k] = -1;
            if (idx < n) {
                int s = src[e0 + idx];
                int d = dst[e0 + idx];
                int b = d >> 7;
                myrec[k] = s | ((d & 127) << 16) | (b << 23);
                myb[k] = b;
                atomicAdd(&smem.b.hist[b], 1);
            }
        }
        __syncthreads();

#pragma unroll
        for (int j = 0; j < 2; ++j) {
            int idx = tid + j * 256;
            int val = smem.b.hist[idx];
            smem.b.cur[idx] = 0;
            if (val > 0) smem.b.gbase[idx] = atomicAdd(&gcur[idx], val);  // val>0 only for idx<NBUCKETS
        }
        __syncthreads();

#pragma unroll
        for (int k = 0; k < CHUNK / 256; ++k) {
            int b = myb[k];
            if (b >= 0) {
                int pos = smem.b.gbase[b] + atomicAdd(&smem.b.cur[b], 1);
                if (pos < BCAP) recs[(size_t)b * BCAP + pos] = myrec[k];
            }
        }
    } else {
        // ---- GEMM: ft[N,64] = feat[N,128] @ W[128,64], all-fp16 LDS.
        // Inner step: 8 ds_read_b64 + 32 v_dot2_f32_f16 per k4.
        int gb = blockIdx.x - NBIN_BLOCKS;

        // stage W -> Bst (fp16, transposed): idx = k*16 + c4
        {
            const float4* W4 = (const float4*)W;
#pragma unroll
            for (int i = 0; i < 8; ++i) {
                int idx = tid + 256 * i;
                int k = idx >> 4;
                int c4 = idx & 15;
                float4 v = W4[idx];
                smem.g.Bst[c4 * 4 + 0][k] = __float2half(v.x);
                smem.g.Bst[c4 * 4 + 1][k] = __float2half(v.y);
                smem.g.Bst[c4 * 4 + 2][k] = __float2half(v.z);
                smem.g.Bst[c4 * 4 + 3][k] = __float2half(v.w);
            }
        }
        // stage feat tile -> As (fp16)
        {
            int row0 = gb * 64;
            const float4* F4 = (const float4*)feat;
#pragma unroll
            for (int i = 0; i < 8; ++i) {
                int idx = tid + 256 * i;
                int r = idx >> 5;
                int c4 = idx & 31;
                float4 v = make_float4(0.f, 0.f, 0.f, 0.f);
                int row = row0 + r;
                if (row < N_NODES) v = F4[(size_t)row * 32 + c4];
                Half4 h;
                h.a = __floats2half2_rn(v.x, v.y);
                h.b = __floats2half2_rn(v.z, v.w);
                *(Half4*)&smem.g.As[r][c4 * 4] = h;  // byte off = r*264 + c4*8, 8B-aligned
            }
        }
        __syncthreads();

        const int tr = tid >> 4;
        const int tc = tid & 15;

        float acc[4][4] = {};
#pragma unroll 4
        for (int k4 = 0; k4 < D_IN / 4; ++k4) {
            H4 a[4], b[4];
#pragma unroll
            for (int i = 0; i < 4; ++i) a[i] = *(const H4*)&smem.g.As[tr * 4 + i][k4 * 4];
#pragma unroll
            for (int c = 0; c < 4; ++c) b[c] = *(const H4*)&smem.g.Bst[tc * 4 + c][k4 * 4];
#pragma unroll
            for (int i = 0; i < 4; ++i)
#pragma unroll
                for (int c = 0; c < 4; ++c)
                    acc[i][c] = dot2acc(a[i].b, b[c].b, dot2acc(a[i].a, b[c].a, acc[i][c]));
        }

        int row0 = gb * 64;
#pragma unroll
        for (int i = 0; i < 4; ++i) {
            int row = row0 + tr * 4 + i;
            if (row < N_NODES) {
                Half4 h;
                h.a = __floats2half2_rn(acc[i][0], acc[i][1]);
                h.b = __floats2half2_rn(acc[i][2], acc[i][3]);
                *(Half4*)&fth[(size_t)row * HF + tc * 4] = h;
            }
        }
    }
}

// ---------------- sort: per-bucket counting sort -> ushort CSR ----------------
// 392 blocks. Single global read pass (recs -> registers), INDEX-based validity,
// wave-scan hist over 128 node slots, scatter into the bucket's L2-hot window.
__global__ __launch_bounds__(256) void sort_kernel(const int* __restrict__ gcur,
                                                   const int* __restrict__ recs,
                                                   unsigned short* __restrict__ csr,
                                                   int2* __restrict__ rows) {
    __shared__ int lhist[256];
    __shared__ int lcur[256];
    __shared__ int wsum[4];

    int tid = threadIdx.x;
    int b = blockIdx.x;
    int cnt = gcur[b]; if (cnt > BCAP) cnt = BCAP;
    const int* rp = recs + (size_t)b * BCAP;

    lhist[tid] = 0;
    __syncthreads();

    int rk[SORT_K];
#pragma unroll
    for (int k = 0; k < SORT_K; ++k) {
        int i = tid + k * 256;
        bool valid = i < cnt;
        rk[k] = valid ? rp[i] : 0;
        if (valid) atomicAdd(&lhist[(rk[k] >> 16) & 127], 1);
    }
    __syncthreads();

    int val = lhist[tid];                 // zero for tid >= 128
    int excl = block_excl_scan(val, wsum);
    lcur[tid] = excl;
    __syncthreads();

    int base = b * BCAP;
#pragma unroll
    for (int k = 0; k < SORT_K; ++k) {
        int i = tid + k * 256;
        if (i < cnt) {
            int p = atomicAdd(&lcur[(rk[k] >> 16) & 127], 1);
            csr[base + p] = (unsigned short)(rk[k] & 0xFFFF);  // src id
        }
    }

    if (tid < 128) {
        int node = (b << 7) + tid;
        if (node < N_NODES) rows[node] = make_int2(base + excl, base + excl + val);
    }
}

// ---------------- fused gather: one wave per node, SIXTEEN edges in flight ----------------
// lane = g*16 + hl: g = edge slot (0..3), hl = feature-quad. 16 lanes cover a
// 64-feature row; head = 4 lanes -> 2 shfl_xor per 4 edges. Softmax without
// max-subtraction (scores bounded, exp in fp32 range).
__global__ __launch_bounds__(256) void gather_kernel(const __half* __restrict__ fth,
                                                     const int2* __restrict__ rows,
                                                     const unsigned short* __restrict__ csr,
                                                     float* __restrict__ out) {
    int node = __builtin_amdgcn_readfirstlane(blockIdx.x * 4 + (threadIdx.x >> 6));
    int lane = threadIdx.x & 63;
    int g = lane >> 4;     // edge slot within group
    int hl = lane & 15;    // feature-quad index

    int2 be = rows[node];
    int beg = be.x;
    int end = be.y;

    H4 a = *(const H4*)&fth[(size_t)node * HF + 4 * hl];

    float acc0 = 0.f, acc1 = 0.f, acc2 = 0.f, acc3 = 0.f, lsum = 0.f;

    for (int i = beg; i < end; i += 16) {
        int s[4];
        bool act[4];
        H4 v[4];
        float p[4];
#pragma unroll
        for (int u = 0; u < 4; ++u) {
            int idx = i + 4 * u + g;
            act[u] = idx < end;
            s[u] = csr[act[u] ? idx : beg];
        }
#pragma unroll
        for (int u = 0; u < 4; ++u) v[u] = *(const H4*)&fth[(size_t)s[u] * HF + 4 * hl];
#pragma unroll
        for (int u = 0; u < 4; ++u) p[u] = dot4h(a, v[u]);
#pragma unroll
        for (int u = 0; u < 4; ++u) p[u] += __shfl_xor(p[u], 1, 64);
#pragma unroll
        for (int u = 0; u < 4; ++u) p[u] += __shfl_xor(p[u], 2, 64);
#pragma unroll
        for (int u = 0; u < 4; ++u) {
            float w = act[u] ? __expf(p[u] * 0.25f) : 0.0f;
            acc0 = fmaf(w, (float)v[u].a[0], acc0);
            acc1 = fmaf(w, (float)v[u].a[1], acc1);
            acc2 = fmaf(w, (float)v[u].b[0], acc2);
            acc3 = fmaf(w, (float)v[u].b[1], acc3);
            lsum += w;
        }
    }

    // reduce across the 4 edge-slots (lanes ^16, ^32 hold same features)
    acc0 += __shfl_xor(acc0, 16, 64);  acc0 += __shfl_xor(acc0, 32, 64);
    acc1 += __shfl_xor(acc1, 16, 64);  acc1 += __shfl_xor(acc1, 32, 64);
    acc2 += __shfl_xor(acc2, 16, 64);  acc2 += __shfl_xor(acc2, 32, 64);
    acc3 += __shfl_xor(acc3, 16, 64);  acc3 += __shfl_xor(acc3, 32, 64);
    lsum += __shfl_xor(lsum, 16, 64);  lsum += __shfl_xor(lsum, 32, 64);

    if (lane < 16) {
        float inv = (lsum > 0.0f) ? 1.0f / lsum : 0.0f;
        *(float4*)&out[(size_t)node * HF + 4 * hl] =
            make_float4(acc0 * inv, acc1 * inv, acc2 * inv, acc3 * inv);
    }
}

extern "C" void kernel_launch(void* const* d_in, const int* in_sizes, int n_in,
                              void* d_out, int out_size, void* d_ws, size_t ws_size,
                              hipStream_t stream) {
    const float* feat = (const float*)d_in[0];
    const float* W = (const float*)d_in[1];
    const int* src = (const int*)d_in[2];
    const int* dst = (const int*)d_in[3];
    float* out = (float*)d_out;

    // workspace layout (all 16B-aligned)
    __half* fth = (__half*)d_ws;                             // N*64 halves (6.4 MB)
    int* recs = (int*)(fth + (size_t)N_NODES * HF);          // NBUCKETS*BCAP ints (4.0 MB)
    unsigned short* csr = (unsigned short*)(recs + (size_t)NBUCKETS * BCAP);  // 2.0 MB
    int2* rows = (int2*)(csr + (size_t)NBUCKETS * BCAP);     // N int2 (0.4 MB)
    int* gcur = (int*)(rows + N_NODES);                      // NBUCKETS ints

    hipMemsetAsync(gcur, 0, NBUCKETS * sizeof(int), stream);
    gemm_bin_kernel<<<NBIN_BLOCKS + GEMM_BLOCKS, 256, 0, stream>>>(feat, W, src, dst,
                                                                   fth, gcur, recs);
    sort_kernel<<<NBUCKETS, 256, 0, stream>>>(gcur, recs, csr, rows);
    gather_kernel<<<N_NODES * 64 / 256, 256, 0, stream>>>(fth, rows, csr, out);
}

// Round 17
// 140.155 us; speedup vs baseline: 1.0878x; 1.0878x over previous
//
#include <hip/hip_runtime.h>
#include <hip/hip_fp16.h>

#define N_NODES 50000
#define N_EDGES 800000
#define D_IN 128
#define HH 4
#define FF 16
#define HF 64  // HH*FF
#define NBUCKETS 392                 // ceil(N_NODES/128); bucket b covers dst in [b*128, b*128+128)
#define BCAP 2560                    // bucket capacity; Poisson(2048) + 11 sigma
#define CHUNK 2048                   // edges per bin block
#define NBIN_BLOCKS ((N_EDGES + CHUNK - 1) / CHUNK)  // 391
#define GEMM_BLOCKS ((N_NODES + 63) / 64)            // 782
#define SORT_K (BCAP / 256)                          // 10 recs per thread in sort

struct __align__(8) Half4 { __half2 a, b; };

typedef _Float16 half2_v __attribute__((ext_vector_type(2)));
struct __align__(8) H4 { half2_v a, b; };

__device__ __forceinline__ float dot2acc(half2_v a, half2_v b, float acc) {
#if __has_builtin(__builtin_amdgcn_fdot2)
    return __builtin_amdgcn_fdot2(a, b, acc, false);
#else
    return acc + (float)a[0] * (float)b[0] + (float)a[1] * (float)b[1];
#endif
}

__device__ __forceinline__ float dot4h(H4 a, H4 v) {
    return dot2acc(a.a, v.a, dot2acc(a.b, v.b, 0.0f));
}

// 256-entry exclusive scan with 2 barriers: wave shfl_up scan + 4-wave combine.
__device__ __forceinline__ int block_excl_scan(int val, int* wsum) {
    int lane = threadIdx.x & 63;
    int wave = threadIdx.x >> 6;
    int incl = val;
#pragma unroll
    for (int off = 1; off < 64; off <<= 1) {
        int t = __shfl_up(incl, off, 64);
        if (lane >= off) incl += t;
    }
    if (lane == 63) wsum[wave] = incl;
    __syncthreads();
    if (threadIdx.x == 0) {
        int a = 0;
#pragma unroll
        for (int w = 0; w < 4; ++w) { int t = wsum[w]; wsum[w] = a; a += t; }
    }
    __syncthreads();
    return incl + wsum[wave] - val;
}

// ---------------- GEMM: ft[N,64] = feat[N,128] @ W[128,64], fp16 LDS ----------------
// As[64][132] halves: read As[tr*4+i][k4*4] -- per-instruction addresses vary only
// by tr (4 values, delta 264 words ≡ 8 mod 32 -> 4 distinct banks), conflict-free.
// Bs[128][64] halves in [k][col] layout (NOT transposed -- R16's [col][k] gave
// per-tc delta ≡ 16 mod 32 -> 8-way conflict, 12.9M counted): read
// Bs[k4*4+j][tc*4] -- per-tc delta = 2 words -> 16 tc x 2 = 32 banks, conflict-free.
// MACs via cvt+fmaf (a is k-contiguous, b is col-contiguous -> no dot2 pairing).
// 32.9 KB LDS -> 4 blocks/CU.
__global__ __launch_bounds__(256, 4) void gemm_kernel(const float* __restrict__ feat,
                                                      const float* __restrict__ W,
                                                      __half* __restrict__ fth) {
    __shared__ __half As[64][132];
    __shared__ __half Bs[128][64];

    int tid = threadIdx.x;

    // stage W -> Bs (fp16, [k][col]): idx = k*16 + c4; coalesced float4 reads,
    // Half4 writes (k-rows alias banks 4-way on write -- 8 instrs total, negligible)
    {
        const float4* W4 = (const float4*)W;
#pragma unroll
        for (int i = 0; i < 8; ++i) {
            int idx = tid + 256 * i;
            int k = idx >> 4;
            int c4 = idx & 15;
            float4 v = W4[idx];
            Half4 h;
            h.a = __floats2half2_rn(v.x, v.y);
            h.b = __floats2half2_rn(v.z, v.w);
            *(Half4*)&Bs[k][c4 * 4] = h;
        }
    }
    // stage feat tile -> As (fp16)
    {
        int row0 = blockIdx.x * 64;
        const float4* F4 = (const float4*)feat;
#pragma unroll
        for (int i = 0; i < 8; ++i) {
            int idx = tid + 256 * i;
            int r = idx >> 5;
            int c4 = idx & 31;
            float4 v = make_float4(0.f, 0.f, 0.f, 0.f);
            int row = row0 + r;
            if (row < N_NODES) v = F4[(size_t)row * 32 + c4];
            Half4 h;
            h.a = __floats2half2_rn(v.x, v.y);
            h.b = __floats2half2_rn(v.z, v.w);
            *(Half4*)&As[r][c4 * 4] = h;  // byte off = r*264 + c4*8, 8B-aligned
        }
    }
    __syncthreads();

    const int tr = tid >> 4;
    const int tc = tid & 15;

    float acc[4][4] = {};
#pragma unroll 4
    for (int k4 = 0; k4 < D_IN / 4; ++k4) {
        float af[4][4], bf[4][4];
#pragma unroll
        for (int i = 0; i < 4; ++i) {
            H4 a = *(const H4*)&As[tr * 4 + i][k4 * 4];
            af[i][0] = (float)a.a[0]; af[i][1] = (float)a.a[1];
            af[i][2] = (float)a.b[0]; af[i][3] = (float)a.b[1];
        }
#pragma unroll
        for (int j = 0; j < 4; ++j) {
            H4 b = *(const H4*)&Bs[k4 * 4 + j][tc * 4];
            bf[j][0] = (float)b.a[0]; bf[j][1] = (float)b.a[1];
            bf[j][2] = (float)b.b[0]; bf[j][3] = (float)b.b[1];
        }
#pragma unroll
        for (int i = 0; i < 4; ++i)
#pragma unroll
            for (int j = 0; j < 4; ++j)
#pragma unroll
                for (int c = 0; c < 4; ++c)
                    acc[i][c] = fmaf(af[i][j], bf[j][c], acc[i][c]);
    }

    int row0 = blockIdx.x * 64;
#pragma unroll
    for (int i = 0; i < 4; ++i) {
        int row = row0 + tr * 4 + i;
        if (row < N_NODES) {
            Half4 h;
            h.a = __floats2half2_rn(acc[i][0], acc[i][1]);
            h.b = __floats2half2_rn(acc[i][2], acc[i][3]);
            *(Half4*)&fth[(size_t)row * HF + tc * 4] = h;
        }
    }
}

// ---------------- bin: edges -> 392 dst-buckets (standalone, 6 KB LDS) ----------------
// rec = src(16b) | (dst&127)<<16 | bucket<<23 (bucket>=256 -> rec NEGATIVE: never
// sign-test recs). hist -> global window alloc -> direct global scatter at
// gbase[b]+cur[b]++. 3 barriers; unconstrained occupancy.
__global__ __launch_bounds__(256) void bin_kernel(const int* __restrict__ src,
                                                  const int* __restrict__ dst,
                                                  int* __restrict__ gcur,
                                                  int* __restrict__ recs) {
    __shared__ int hist[512], cur[512], gbase[512];  // 392 used

    int tid = threadIdx.x;
    int e0 = blockIdx.x * CHUNK;
    int n = N_EDGES - e0; if (n > CHUNK) n = CHUNK;

    hist[tid] = 0;
    hist[tid + 256] = 0;
    __syncthreads();

    int myrec[CHUNK / 256];
    int myb[CHUNK / 256];
#pragma unroll
    for (int k = 0; k < CHUNK / 256; ++k) {
        int idx = tid + k * 256;
        myb[k] = -1;
        if (idx < n) {
            int s = src[e0 + idx];
            int d = dst[e0 + idx];
            int b = d >> 7;
            myrec[k] = s | ((d & 127) << 16) | (b << 23);
            myb[k] = b;
            atomicAdd(&hist[b], 1);
        }
    }
    __syncthreads();

#pragma unroll
    for (int j = 0; j < 2; ++j) {
        int idx = tid + j * 256;
        int val = hist[idx];
        cur[idx] = 0;
        if (val > 0) gbase[idx] = atomicAdd(&gcur[idx], val);  // val>0 only for idx<NBUCKETS
    }
    __syncthreads();

#pragma unroll
    for (int k = 0; k < CHUNK / 256; ++k) {
        int b = myb[k];
        if (b >= 0) {
            int pos = gbase[b] + atomicAdd(&cur[b], 1);
            if (pos < BCAP) recs[(size_t)b * BCAP + pos] = myrec[k];
        }
    }
}

// ---------------- sort: per-bucket counting sort -> ushort CSR ----------------
// 392 blocks. Single global read pass (recs -> registers), INDEX-based validity,
// wave-scan hist over 128 node slots, scatter into the bucket's L2-hot window.
__global__ __launch_bounds__(256) void sort_kernel(const int* __restrict__ gcur,
                                                   const int* __restrict__ recs,
                                                   unsigned short* __restrict__ csr,
                                                   int2* __restrict__ rows) {
    __shared__ int lhist[256];
    __shared__ int lcur[256];
    __shared__ int wsum[4];

    int tid = threadIdx.x;
    int b = blockIdx.x;
    int cnt = gcur[b]; if (cnt > BCAP) cnt = BCAP;
    const int* rp = recs + (size_t)b * BCAP;

    lhist[tid] = 0;
    __syncthreads();

    int rk[SORT_K];
#pragma unroll
    for (int k = 0; k < SORT_K; ++k) {
        int i = tid + k * 256;
        bool valid = i < cnt;
        rk[k] = valid ? rp[i] : 0;
        if (valid) atomicAdd(&lhist[(rk[k] >> 16) & 127], 1);
    }
    __syncthreads();

    int val = lhist[tid];                 // zero for tid >= 128
    int excl = block_excl_scan(val, wsum);
    lcur[tid] = excl;
    __syncthreads();

    int base = b * BCAP;
#pragma unroll
    for (int k = 0; k < SORT_K; ++k) {
        int i = tid + k * 256;
        if (i < cnt) {
            int p = atomicAdd(&lcur[(rk[k] >> 16) & 127], 1);
            csr[base + p] = (unsigned short)(rk[k] & 0xFFFF);  // src id
        }
    }

    if (tid < 128) {
        int node = (b << 7) + tid;
        if (node < N_NODES) rows[node] = make_int2(base + excl, base + excl + val);
    }
}

// ---------------- fused gather: one wave per node, SIXTEEN edges in flight ----------------
// lane = g*16 + hl: g = edge slot (0..3), hl = feature-quad. 16 lanes cover a
// 64-feature row; head = 4 lanes -> 2 shfl_xor per 4 edges. Softmax without
// max-subtraction (scores bounded, exp in fp32 range).
__global__ __launch_bounds__(256) void gather_kernel(const __half* __restrict__ fth,
                                                     const int2* __restrict__ rows,
                                                     const unsigned short* __restrict__ csr,
                                                     float* __restrict__ out) {
    int node = __builtin_amdgcn_readfirstlane(blockIdx.x * 4 + (threadIdx.x >> 6));
    int lane = threadIdx.x & 63;
    int g = lane >> 4;     // edge slot within group
    int hl = lane & 15;    // feature-quad index

    int2 be = rows[node];
    int beg = be.x;
    int end = be.y;

    H4 a = *(const H4*)&fth[(size_t)node * HF + 4 * hl];

    float acc0 = 0.f, acc1 = 0.f, acc2 = 0.f, acc3 = 0.f, lsum = 0.f;

    for (int i = beg; i < end; i += 16) {
        int s[4];
        bool act[4];
        H4 v[4];
        float p[4];
#pragma unroll
        for (int u = 0; u < 4; ++u) {
            int idx = i + 4 * u + g;
            act[u] = idx < end;
            s[u] = csr[act[u] ? idx : beg];
        }
#pragma unroll
        for (int u = 0; u < 4; ++u) v[u] = *(const H4*)&fth[(size_t)s[u] * HF + 4 * hl];
#pragma unroll
        for (int u = 0; u < 4; ++u) p[u] = dot4h(a, v[u]);
#pragma unroll
        for (int u = 0; u < 4; ++u) p[u] += __shfl_xor(p[u], 1, 64);
#pragma unroll
        for (int u = 0; u < 4; ++u) p[u] += __shfl_xor(p[u], 2, 64);
#pragma unroll
        for (int u = 0; u < 4; ++u) {
            float w = act[u] ? __expf(p[u] * 0.25f) : 0.0f;
            acc0 = fmaf(w, (float)v[u].a[0], acc0);
            acc1 = fmaf(w, (float)v[u].a[1], acc1);
            acc2 = fmaf(w, (float)v[u].b[0], acc2);
            acc3 = fmaf(w, (float)v[u].b[1], acc3);
            lsum += w;
        }
    }

    // reduce across the 4 edge-slots (lanes ^16, ^32 hold same features)
    acc0 += __shfl_xor(acc0, 16, 64);  acc0 += __shfl_xor(acc0, 32, 64);
    acc1 += __shfl_xor(acc1, 16, 64);  acc1 += __shfl_xor(acc1, 32, 64);
    acc2 += __shfl_xor(acc2, 16, 64);  acc2 += __shfl_xor(acc2, 32, 64);
    acc3 += __shfl_xor(acc3, 16, 64);  acc3 += __shfl_xor(acc3, 32, 64);
    lsum += __shfl_xor(lsum, 16, 64);  lsum += __shfl_xor(lsum, 32, 64);

    if (lane < 16) {
        float inv = (lsum > 0.0f) ? 1.0f / lsum : 0.0f;
        *(float4*)&out[(size_t)node * HF + 4 * hl] =
            make_float4(acc0 * inv, acc1 * inv, acc2 * inv, acc3 * inv);
    }
}

extern "C" void kernel_launch(void* const* d_in, const int* in_sizes, int n_in,
                              void* d_out, int out_size, void* d_ws, size_t ws_size,
                              hipStream_t stream) {
    const float* feat = (const float*)d_in[0];
    const float* W = (const float*)d_in[1];
    const int* src = (const int*)d_in[2];
    const int* dst = (const int*)d_in[3];
    float* out = (float*)d_out;

    // workspace layout (all 16B-aligned)
    __half* fth = (__half*)d_ws;                             // N*64 halves (6.4 MB)
    int* recs = (int*)(fth + (size_t)N_NODES * HF);          // NBUCKETS*BCAP ints (4.0 MB)
    unsigned short* csr = (unsigned short*)(recs + (size_t)NBUCKETS * BCAP);  // 2.0 MB
    int2* rows = (int2*)(csr + (size_t)NBUCKETS * BCAP);     // N int2 (0.4 MB)
    int* gcur = (int*)(rows + N_NODES);                      // NBUCKETS ints

    hipMemsetAsync(gcur, 0, NBUCKETS * sizeof(int), stream);
    gemm_kernel<<<GEMM_BLOCKS, 256, 0, stream>>>(feat, W, fth);
    bin_kernel<<<NBIN_BLOCKS, 256, 0, stream>>>(src, dst, gcur, recs);
    sort_kernel<<<NBUCKETS, 256, 0, stream>>>(gcur, recs, csr, rows);
    gather_kernel<<<N_NODES * 64 / 256, 256, 0, stream>>>(fth, rows, csr, out);
}